// Round 6
// baseline (249.506 us; speedup 1.0000x reference)
//
#include <hip/hip_runtime.h>
#include <math.h>

// SegmentedTensorSquareSelfInteraction on MI355X (gfx950) — fused, streaming-B, 2 blocks/CU.
// N=32768, MUL0=256, MUL1=128, G=64, INV_DIM=448, used gates=576, out=(N,640) fp32
//
// R6: BM=32 + 1x8 wave layout (MT=2) -> LDS 71,808 B -> 2 blocks/CU (R4's TLP) while
//     keeping B-fragment reuse high enough to stay out of the L2-bound regime (R5 lesson:
//     1.3 GB B-traffic is fine, 2.4 GB is not). launch_bounds(512,4); acc max 40 VGPR.
//     wcast: dst-indexed, one coalesced uint4 write/thread. Stage A: packed uint2 writes.
//
// Two dispatches:
//  1. wcast : weights -> bf16 fragment order BF[tile][kc][lane][8], zero-padded tiles.
//  2. fused : per block of 32 nodes, whole chain, zero HBM intermediates, barrier-free
//             GEMM k-loops (B streamed from L2-resident fragment-ordered weights):
//     A: s_all -> LDS sa[32][472]
//     B: h = silu(sa @ W1 * s1) -> LDS hb      (MT=2, NT=4, pad 512)
//     C: gates = hb @ W2 * s1 (MT=2, NT=5, pad 640); u = sa*g0 -> hb; g1 -> LDS
//        wmat[(r*3+i)][m] = v*g1 -> overlays sa ([96][136])
//     D: o0 = u @ Wl0 * s1 (MT=2, NT=2) -> LayerNorm -> out[:, :256]
//     E: o1 = wmat @ Wl1 * s2 (MT=6, NT=1) -> RMS over (3,128) -> out[:, 256:640]
// LDS: sa 30,208 + hb 30,208 + g1 8,192 + red 3,200 = 71,808 B -> 2 blocks/CU, 16 waves/CU.
// ws usage: 1,294,336 bytes (fragment-ordered bf16 weights only).

typedef float floatx4 __attribute__((ext_vector_type(4)));
typedef __bf16 bf16x8 __attribute__((ext_vector_type(8)));

__device__ __forceinline__ unsigned short f2bf(float f) {
    __bf16 h = (__bf16)f;                    // RNE; compiler can pair into v_cvt_pk_bf16_f32
    return __builtin_bit_cast(unsigned short, h);
}
__device__ __forceinline__ float bf2f(unsigned short u) {
    union { unsigned u; float f; } v; v.u = ((unsigned)u) << 16; return v.f;
}

// ---------------------------------------------------------------- weight cast
// Dst-indexed: thread owns one fragment octet (matrix, tile t, kc, lane) and writes
// one coalesced uint4. Reads 8 floats W[kc*32+q*8+e][col=t*16+l15] (col-parallel across
// lanes -> each 8-row group touched as full 64B lines; weights are L2-resident).
__global__ __launch_bounds__(256) void wcast_kernel(
    const float* __restrict__ W1, const float* __restrict__ W2,
    const float* __restrict__ Wl0, const float* __restrict__ Wl1,
    unsigned short* __restrict__ W1F, unsigned short* __restrict__ W2F,
    unsigned short* __restrict__ Wl0F, unsigned short* __restrict__ Wl1F)
{
    int idx = blockIdx.x * 256 + threadIdx.x;   // one per 8 dst shorts
    const float* src; unsigned short* dst;
    int NKC, ld, colTrue, r;
    if (idx < 28672) {                        // W1F: 32 tiles x 14 kc x 64 lanes (512x448)
        r = idx; src = W1; dst = W1F; NKC = 14; ld = 448; colTrue = 448;
    } else if (idx < 64512) {                 // W2F: 40 tiles x 14 kc x 64 (640x448)
        r = idx - 28672; src = W2; dst = W2F; NKC = 14; ld = 832; colTrue = 576;
    } else if (idx < 78848) {                 // Wl0F: 16 tiles x 14 kc x 64 (256x448)
        r = idx - 64512; src = Wl0; dst = Wl0F; NKC = 14; ld = 256; colTrue = 256;
    } else if (idx < 80896) {                 // Wl1F: 8 tiles x 4 kc x 64 (128x128)
        r = idx - 78848; src = Wl1; dst = Wl1F; NKC = 4; ld = 128; colTrue = 128;
    } else return;
    int lane = r & 63, kc = (r >> 6) % NKC, t = (r >> 6) / NKC;
    int col = t * 16 + (lane & 15);
    int k0  = kc * 32 + (lane >> 4) * 8;
    unsigned short v[8];
    #pragma unroll
    for (int e = 0; e < 8; ++e)
        v[e] = (col < colTrue) ? f2bf(src[(size_t)(k0 + e) * ld + col]) : (unsigned short)0;
    *(uint4*)(dst + (size_t)r * 8) = *(const uint4*)v;
}

// ---------------------------------------------------------------- streaming GEMM core
// acc[MT][NT] += A_lds[rows] @ B (fragment-ordered global, L2-resident). No barriers,
// no LDS staging. Wave wn owns N-tiles {wn + 8*j}. Each B-fragment feeds MT MFMAs.
template<int MT, int NT, int NKC>
__device__ __forceinline__ void gemm_stream(
    const unsigned short* __restrict__ BF,
    const unsigned short* __restrict__ Albs, const int ldsA, const int rowBase,
    const int lane, const int l15, const int quad, const int wn,
    floatx4 (&acc)[MT][NT])
{
    const unsigned short* bp[NT];
    #pragma unroll
    for (int j = 0; j < NT; ++j)
        bp[j] = BF + ((size_t)(wn + 8 * j) * NKC * 64 + lane) * 8;
    #pragma unroll
    for (int kc = 0; kc < NKC; ++kc) {
        bf16x8 af[MT];
        #pragma unroll
        for (int mt = 0; mt < MT; ++mt)
            af[mt] = *(const bf16x8*)&Albs[(rowBase + mt * 16 + l15) * ldsA + kc * 32 + quad * 8];
        #pragma unroll
        for (int j = 0; j < NT; ++j) {
            bf16x8 bfv = *(const bf16x8*)(bp[j] + kc * 512);
            #pragma unroll
            for (int mt = 0; mt < MT; ++mt)
                acc[mt][j] = __builtin_amdgcn_mfma_f32_16x16x32_bf16(af[mt], bfv, acc[mt][j], 0, 0, 0);
        }
    }
}

// ---------------------------------------------------------------- fused megakernel
__global__ __launch_bounds__(512, 4) void fused_kernel(
    const float* __restrict__ x,
    const unsigned short* __restrict__ W1F,
    const unsigned short* __restrict__ W2F,
    const unsigned short* __restrict__ Wl0F,
    const unsigned short* __restrict__ Wl1F,
    float* __restrict__ out)
{
    __shared__ unsigned short sa[32][472];   // s_all; later wmat overlay [96][136]
    __shared__ unsigned short hb[32][472];   // h, then u
    __shared__ unsigned short g1[32][128];   // g1o gates
    __shared__ float red[800];               // LN sv[32][8] | sq @256 ; E q[96][8] ; rms @768

    const int tid  = threadIdx.x;
    const int lane = tid & 63;
    const int l15  = lane & 15;
    const int quad = lane >> 4;
    const int wn   = tid >> 6;      // 0..7 : N-tile = wn + 8*j (all waves own all rows)
    const int n0   = blockIdx.x * 32;

    const float s1 = 0.047245559f;  // 1/sqrt(448)
    const float s2 = 0.088388348f;  // 1/sqrt(128)

    // ---- stage A: s_all -> sa ----
    {
        const int r = tid >> 4, sub = tid & 15;    // 16 threads per row
        const float* xr = x + (size_t)(n0 + r) * 640;
        #pragma unroll
        for (int i = 0; i < 4; ++i) {              // s part: 64 float4 per row
            int c4 = i * 16 + sub;
            float4 f = *(const float4*)(xr + c4 * 4);
            uint2 p;
            p.x = (unsigned)f2bf(f.x) | ((unsigned)f2bf(f.y) << 16);
            p.y = (unsigned)f2bf(f.z) | ((unsigned)f2bf(f.w) << 16);
            *(uint2*)&sa[r][c4 * 4] = p;
        }
        const float* xv = xr + 256;
        #pragma unroll
        for (int i = 0; i < 4; ++i) {              // t0 part: 64 groups per row
            int g = i * 16 + sub;
            const float2* vg = (const float2*)(xv + 6 * g);
            float2 p0 = vg[0], p1 = vg[1], p2 = vg[2];
            float ax = p0.x, ay = p0.y, az = p1.x;
            float bx = p1.y, by = p2.x, bz = p2.y;
            float aa = ax*ax + ay*ay + az*az;
            float ab = ax*bx + ay*by + az*bz;
            float bb = bx*bx + by*by + bz*bz;
            const float ISQ3 = 0.57735026918962576f;
            const float SQ2  = 1.41421356237309505f;
            sa[r][256 + 3*g]     = f2bf(aa * ISQ3);
            sa[r][256 + 3*g + 1] = f2bf(SQ2 * ab * ISQ3);
            sa[r][256 + 3*g + 2] = f2bf(bb * ISQ3);
        }
    }
    __syncthreads();                               // sa ready

    // ---- stage B: h = silu(sa @ W1 * s1) -> hb  (pad 512, skip tiles >= 28) ----
    {
        floatx4 acc[2][4] = {};
        gemm_stream<2,4,14>(W1F, &sa[0][0], 472, 0, lane, l15, quad, wn, acc);
        #pragma unroll
        for (int j = 0; j < 4; ++j) {
            const int colb = (wn + 8*j) * 16;      // wave-uniform
            if (colb < 448) {
                const int col = colb + l15;
                #pragma unroll
                for (int mt = 0; mt < 2; ++mt)
                    #pragma unroll
                    for (int r = 0; r < 4; ++r) {
                        float v = acc[mt][j][r] * s1;
                        v = v / (1.f + __expf(-v));
                        hb[mt*16 + quad*4 + r][col] = f2bf(v);
                    }
            }
        }
    }
    __syncthreads();                               // hb(h) ready

    // ---- stage C: gates = hb @ W2 * s1 (pad 640); u -> hb; g1 -> g1[][] ----
    {
        floatx4 acc[2][5] = {};
        gemm_stream<2,5,14>(W2F, &hb[0][0], 472, 0, lane, l15, quad, wn, acc);
        __syncthreads();                           // all hb(h) reads complete
        #pragma unroll
        for (int j = 0; j < 5; ++j) {
            const int colb = (wn + 8*j) * 16;      // wave-uniform, 0..624
            if (colb < 448) {                      // g0 -> u = sa * g0
                const int col = colb + l15;
                #pragma unroll
                for (int mt = 0; mt < 2; ++mt)
                    #pragma unroll
                    for (int r = 0; r < 4; ++r) {
                        const int row = mt*16 + quad*4 + r;
                        hb[row][col] = f2bf(bf2f(sa[row][col]) * (acc[mt][j][r] * s1));
                    }
            } else if (colb < 576) {               // g1o
                const int m = colb - 448 + l15;
                #pragma unroll
                for (int mt = 0; mt < 2; ++mt)
                    #pragma unroll
                    for (int r = 0; r < 4; ++r) {
                        const int row = mt*16 + quad*4 + r;
                        g1[row][m] = f2bf(acc[mt][j][r] * s1);
                    }
            }
        }
    }
    __syncthreads();                               // u/g1 ready; sa dead

    // ---- wmat build: wmat[(r*3+i)][m] = v[r][m][i] * g1[r][m] -> overlays sa ----
    {
        unsigned short* wmp = &sa[0][0];           // [96][136]
        #pragma unroll
        for (int e0 = 0; e0 < 3072; e0 += 512) {   // 32 rows * 96 float4
            int e4 = e0 + tid;
            int rl = e4 / 96;
            int c4 = (e4 - rl * 96) * 4;           // float index in v-row (0..383)
            float4 xv = *(const float4*)(x + (size_t)(n0 + rl) * 640 + 256 + c4);
            float vv[4] = {xv.x, xv.y, xv.z, xv.w};
            #pragma unroll
            for (int d = 0; d < 4; ++d) {
                int rem = c4 + d;
                int m = rem / 3;
                int i = rem - 3 * m;
                wmp[(rl * 3 + i) * 136 + m] = f2bf(vv[d] * bf2f(g1[rl][m]));
            }
        }
    }
    __syncthreads();                               // wmat ready

    // ---- stage D: o0 = u @ Wl0 * s1 -> LayerNorm -> out[:, :256] ----
    {
        floatx4 acc[2][2] = {};
        gemm_stream<2,2,14>(Wl0F, &hb[0][0], 472, 0, lane, l15, quad, wn, acc);
        #pragma unroll
        for (int mt = 0; mt < 2; ++mt)
            #pragma unroll
            for (int r = 0; r < 4; ++r) {
                float sv = 0.f, sq = 0.f;
                #pragma unroll
                for (int j = 0; j < 2; ++j) {
                    float v = acc[mt][j][r] * s1;
                    sv += v; sq += v * v;
                }
                #pragma unroll
                for (int off = 1; off <= 8; off <<= 1) {
                    sv += __shfl_xor(sv, off);
                    sq += __shfl_xor(sq, off);
                }
                if (l15 == 0) {
                    const int row = mt*16 + quad*4 + r;
                    red[row * 8 + wn]       = sv;
                    red[256 + row * 8 + wn] = sq;
                }
            }
        __syncthreads();                           // LN partials ready
        #pragma unroll
        for (int mt = 0; mt < 2; ++mt)
            #pragma unroll
            for (int r = 0; r < 4; ++r) {
                const int row = mt*16 + quad*4 + r;
                float ts = 0.f, tq = 0.f;
                #pragma unroll
                for (int w2 = 0; w2 < 8; ++w2) {
                    ts += red[row*8 + w2];
                    tq += red[256 + row*8 + w2];
                }
                float mu  = ts * (1.f/256.f);
                float var = tq * (1.f/256.f) - mu * mu;
                float rln = rsqrtf(var + 1e-6f);
                float* orow = out + (size_t)(n0 + row) * 640;
                #pragma unroll
                for (int j = 0; j < 2; ++j)
                    orow[(wn + 8*j)*16 + l15] = (acc[mt][j][r] * s1 - mu) * rln;
            }
    }
    __syncthreads();                               // stage-D red reads done before E writes red

    // ---- stage E: o1 = wmat @ Wl1 * s2 -> RMS over (3,128) -> out[:, 256:640] ----
    {
        floatx4 acc[6][1] = {};
        gemm_stream<6,1,4>(Wl1F, &sa[0][0] /*wmat*/, 136, 0, lane, l15, quad, wn, acc);
        #pragma unroll
        for (int mt = 0; mt < 6; ++mt)
            #pragma unroll
            for (int r = 0; r < 4; ++r) {
                float v = acc[mt][0][r] * s2;
                float q = v * v;
                #pragma unroll
                for (int off = 1; off <= 8; off <<= 1) q += __shfl_xor(q, off);
                if (l15 == 0) {
                    const int row = mt*16 + quad*4 + r;
                    red[row * 8 + wn] = q;
                }
            }
        __syncthreads();
        if (tid < 32) {                            // per-node rrms
            float s = 0.f;
            #pragma unroll
            for (int rr = 0; rr < 3; ++rr)
                #pragma unroll
                for (int w2 = 0; w2 < 8; ++w2)
                    s += red[(tid*3 + rr) * 8 + w2];
            red[768 + tid] = rsqrtf(s * (1.f/384.f) + 1e-6f);
        }
        __syncthreads();
        #pragma unroll
        for (int mt = 0; mt < 6; ++mt)
            #pragma unroll
            for (int r = 0; r < 4; ++r) {
                const int row = mt*16 + quad*4 + r;
                const int nl  = row / 3;
                const int i   = row - 3 * nl;
                const float rms = red[768 + nl];
                float* op = out + (size_t)(n0 + nl) * 640 + 256 + i;
                op[3 * (wn*16 + l15)] = acc[mt][0][r] * s2 * rms;
            }
    }
}

// ---------------------------------------------------------------- launch
extern "C" void kernel_launch(void* const* d_in, const int* in_sizes, int n_in,
                              void* d_out, int out_size, void* d_ws, size_t ws_size,
                              hipStream_t stream) {
    const float* x   = (const float*)d_in[0];
    const float* W1  = (const float*)d_in[1];
    const float* W2  = (const float*)d_in[2];
    const float* Wl0 = (const float*)d_in[3];
    const float* Wl1 = (const float*)d_in[4];
    float* out = (float*)d_out;
    char* ws = (char*)d_ws;

    unsigned short* W1F  = (unsigned short*)(ws + 0);         // 458,752 B (512x448)
    unsigned short* W2F  = (unsigned short*)(ws + 458752);    // 573,440 B (640x448)
    unsigned short* Wl0F = (unsigned short*)(ws + 1032192);   // 229,376 B (256x448)
    unsigned short* Wl1F = (unsigned short*)(ws + 1261568);   //  32,768 B (128x128)
    // peak ws: 1,294,336 bytes

    wcast_kernel<<<dim3(316), dim3(256), 0, stream>>>(W1, W2, Wl0, Wl1, W1F, W2F, Wl0F, Wl1F);
    fused_kernel<<<dim3(1024), dim3(512), 0, stream>>>(x, W1F, W2F, Wl0F, Wl1F, out);
}

// Round 7
// 235.857 us; speedup vs baseline: 1.0579x; 1.0579x over previous
//
#include <hip/hip_runtime.h>
#include <math.h>

// SegmentedTensorSquareSelfInteraction on MI355X (gfx950) — fused, streaming-B, pipelined.
// N=32768, MUL0=256, MUL1=128, G=64, INV_DIM=448, used gates=576, out=(N,640) fp32
//
// R7: explicit 2-deep register ping-pong prefetch in gemm_stream. R6 evidence: compiler
//     allocated 64 VGPR and serialized each B-load -> MFMA (per-kc ~3.7K cycles vs ~90 of
//     issue). Static-index reg sets (a0/b0, a1/b1), loads for kc+1 issued before kc's MFMAs.
//     Geometry unchanged from R6: BM=32, 1x8 waves, MT=2, LDS 71,808 B, 2 blocks/CU.
//
// Two dispatches:
//  1. wcast : weights -> bf16 fragment order BF[tile][kc][lane][8], zero-padded tiles.
//  2. fused : per block of 32 nodes, whole chain, zero HBM intermediates:
//     A: s_all -> LDS sa[32][472]
//     B: h = silu(sa @ W1 * s1) -> LDS hb      (MT=2, NT=4, pad 512)
//     C: gates = hb @ W2 * s1 (MT=2, NT=5, pad 640); u = sa*g0 -> hb; g1 -> LDS
//        wmat[(r*3+i)][m] = v*g1 -> overlays sa ([96][136])
//     D: o0 = u @ Wl0 * s1 (MT=2, NT=2) -> LayerNorm -> out[:, :256]
//     E: o1 = wmat @ Wl1 * s2 (MT=6, NT=1) -> RMS over (3,128) -> out[:, 256:640]
// LDS: sa 30,208 + hb 30,208 + g1 8,192 + red 3,200 = 71,808 B -> 2 blocks/CU, 16 waves/CU.
// ws usage: 1,294,336 bytes (fragment-ordered bf16 weights only).

typedef float floatx4 __attribute__((ext_vector_type(4)));
typedef __bf16 bf16x8 __attribute__((ext_vector_type(8)));

__device__ __forceinline__ unsigned short f2bf(float f) {
    __bf16 h = (__bf16)f;                    // RNE; compiler can pair into v_cvt_pk_bf16_f32
    return __builtin_bit_cast(unsigned short, h);
}
__device__ __forceinline__ float bf2f(unsigned short u) {
    union { unsigned u; float f; } v; v.u = ((unsigned)u) << 16; return v.f;
}

// ---------------------------------------------------------------- weight cast
// Dst-indexed: thread owns one fragment octet (matrix, tile t, kc, lane) and writes
// one coalesced uint4.
__global__ __launch_bounds__(256) void wcast_kernel(
    const float* __restrict__ W1, const float* __restrict__ W2,
    const float* __restrict__ Wl0, const float* __restrict__ Wl1,
    unsigned short* __restrict__ W1F, unsigned short* __restrict__ W2F,
    unsigned short* __restrict__ Wl0F, unsigned short* __restrict__ Wl1F)
{
    int idx = blockIdx.x * 256 + threadIdx.x;   // one per 8 dst shorts
    const float* src; unsigned short* dst;
    int NKC, ld, colTrue, r;
    if (idx < 28672) {                        // W1F: 32 tiles x 14 kc x 64 lanes (512x448)
        r = idx; src = W1; dst = W1F; NKC = 14; ld = 448; colTrue = 448;
    } else if (idx < 64512) {                 // W2F: 40 tiles x 14 kc x 64 (640x448)
        r = idx - 28672; src = W2; dst = W2F; NKC = 14; ld = 832; colTrue = 576;
    } else if (idx < 78848) {                 // Wl0F: 16 tiles x 14 kc x 64 (256x448)
        r = idx - 64512; src = Wl0; dst = Wl0F; NKC = 14; ld = 256; colTrue = 256;
    } else if (idx < 80896) {                 // Wl1F: 8 tiles x 4 kc x 64 (128x128)
        r = idx - 78848; src = Wl1; dst = Wl1F; NKC = 4; ld = 128; colTrue = 128;
    } else return;
    int lane = r & 63, kc = (r >> 6) % NKC, t = (r >> 6) / NKC;
    int col = t * 16 + (lane & 15);
    int k0  = kc * 32 + (lane >> 4) * 8;
    unsigned short v[8];
    #pragma unroll
    for (int e = 0; e < 8; ++e)
        v[e] = (col < colTrue) ? f2bf(src[(size_t)(k0 + e) * ld + col]) : (unsigned short)0;
    *(uint4*)(dst + (size_t)r * 8) = *(const uint4*)v;
}

// ---------------------------------------------------------------- streaming GEMM core
// acc[MT][NT] += A_lds[rows] @ B (fragment-ordered global, L2-resident).
// 2-deep software pipeline: register sets {a0,b0} / {a1,b1}; loads for kc+1 are issued
// in program order BEFORE the MFMAs of kc, so L2 latency hides under the MFMA cluster
// (and under the other 3 waves/SIMD). All register indices compile-time (no scratch).
template<int MT, int NT, int NKC>
__device__ __forceinline__ void gemm_stream(
    const unsigned short* __restrict__ BF,
    const unsigned short* __restrict__ Albs, const int ldsA, const int rowBase,
    const int lane, const int l15, const int quad, const int wn,
    floatx4 (&acc)[MT][NT])
{
    static_assert(NKC % 2 == 0, "pipeline assumes even NKC");
    const unsigned short* bp[NT];
    #pragma unroll
    for (int j = 0; j < NT; ++j)
        bp[j] = BF + ((size_t)(wn + 8 * j) * NKC * 64 + lane) * 8;
    const unsigned short* ap = Albs + (size_t)(rowBase + l15) * ldsA + quad * 8;

    bf16x8 a0[MT], b0[NT], a1[MT], b1[NT];
    #pragma unroll
    for (int mt = 0; mt < MT; ++mt) a0[mt] = *(const bf16x8*)(ap + mt * 16 * ldsA);
    #pragma unroll
    for (int j = 0; j < NT; ++j)    b0[j]  = *(const bf16x8*)(bp[j]);

    #pragma unroll
    for (int kc2 = 0; kc2 < NKC / 2; ++kc2) {
        const int k1 = 2 * kc2 + 1, k2 = 2 * kc2 + 2;
        // prefetch kc=k1 into set1
        #pragma unroll
        for (int mt = 0; mt < MT; ++mt)
            a1[mt] = *(const bf16x8*)(ap + mt * 16 * ldsA + k1 * 32);
        #pragma unroll
        for (int j = 0; j < NT; ++j)
            b1[j] = *(const bf16x8*)(bp[j] + k1 * 512);
        // compute set0 (kc=2*kc2)
        #pragma unroll
        for (int j = 0; j < NT; ++j)
            #pragma unroll
            for (int mt = 0; mt < MT; ++mt)
                acc[mt][j] = __builtin_amdgcn_mfma_f32_16x16x32_bf16(a0[mt], b0[j], acc[mt][j], 0, 0, 0);
        // prefetch kc=k2 into set0
        if (k2 < NKC) {
            #pragma unroll
            for (int mt = 0; mt < MT; ++mt)
                a0[mt] = *(const bf16x8*)(ap + mt * 16 * ldsA + k2 * 32);
            #pragma unroll
            for (int j = 0; j < NT; ++j)
                b0[j] = *(const bf16x8*)(bp[j] + k2 * 512);
        }
        // compute set1 (kc=k1)
        #pragma unroll
        for (int j = 0; j < NT; ++j)
            #pragma unroll
            for (int mt = 0; mt < MT; ++mt)
                acc[mt][j] = __builtin_amdgcn_mfma_f32_16x16x32_bf16(a1[mt], b1[j], acc[mt][j], 0, 0, 0);
    }
}

// ---------------------------------------------------------------- fused megakernel
__global__ __launch_bounds__(512, 4) void fused_kernel(
    const float* __restrict__ x,
    const unsigned short* __restrict__ W1F,
    const unsigned short* __restrict__ W2F,
    const unsigned short* __restrict__ Wl0F,
    const unsigned short* __restrict__ Wl1F,
    float* __restrict__ out)
{
    __shared__ unsigned short sa[32][472];   // s_all; later wmat overlay [96][136]
    __shared__ unsigned short hb[32][472];   // h, then u
    __shared__ unsigned short g1[32][128];   // g1o gates
    __shared__ float red[800];               // LN sv[32][8] | sq @256 ; E q[96][8] ; rms @768

    const int tid  = threadIdx.x;
    const int lane = tid & 63;
    const int l15  = lane & 15;
    const int quad = lane >> 4;
    const int wn   = tid >> 6;      // 0..7 : N-tile = wn + 8*j (all waves own all rows)
    const int n0   = blockIdx.x * 32;

    const float s1 = 0.047245559f;  // 1/sqrt(448)
    const float s2 = 0.088388348f;  // 1/sqrt(128)

    // ---- stage A: s_all -> sa ----
    {
        const int r = tid >> 4, sub = tid & 15;    // 16 threads per row
        const float* xr = x + (size_t)(n0 + r) * 640;
        #pragma unroll
        for (int i = 0; i < 4; ++i) {              // s part: 64 float4 per row
            int c4 = i * 16 + sub;
            float4 f = *(const float4*)(xr + c4 * 4);
            uint2 p;
            p.x = (unsigned)f2bf(f.x) | ((unsigned)f2bf(f.y) << 16);
            p.y = (unsigned)f2bf(f.z) | ((unsigned)f2bf(f.w) << 16);
            *(uint2*)&sa[r][c4 * 4] = p;
        }
        const float* xv = xr + 256;
        #pragma unroll
        for (int i = 0; i < 4; ++i) {              // t0 part: 64 groups per row
            int g = i * 16 + sub;
            const float2* vg = (const float2*)(xv + 6 * g);
            float2 p0 = vg[0], p1 = vg[1], p2 = vg[2];
            float ax = p0.x, ay = p0.y, az = p1.x;
            float bx = p1.y, by = p2.x, bz = p2.y;
            float aa = ax*ax + ay*ay + az*az;
            float ab = ax*bx + ay*by + az*bz;
            float bb = bx*bx + by*by + bz*bz;
            const float ISQ3 = 0.57735026918962576f;
            const float SQ2  = 1.41421356237309505f;
            sa[r][256 + 3*g]     = f2bf(aa * ISQ3);
            sa[r][256 + 3*g + 1] = f2bf(SQ2 * ab * ISQ3);
            sa[r][256 + 3*g + 2] = f2bf(bb * ISQ3);
        }
    }
    __syncthreads();                               // sa ready

    // ---- stage B: h = silu(sa @ W1 * s1) -> hb  (pad 512, skip tiles >= 28) ----
    {
        floatx4 acc[2][4] = {};
        gemm_stream<2,4,14>(W1F, &sa[0][0], 472, 0, lane, l15, quad, wn, acc);
        #pragma unroll
        for (int j = 0; j < 4; ++j) {
            const int colb = (wn + 8*j) * 16;      // wave-uniform
            if (colb < 448) {
                const int col = colb + l15;
                #pragma unroll
                for (int mt = 0; mt < 2; ++mt)
                    #pragma unroll
                    for (int r = 0; r < 4; ++r) {
                        float v = acc[mt][j][r] * s1;
                        v = v / (1.f + __expf(-v));
                        hb[mt*16 + quad*4 + r][col] = f2bf(v);
                    }
            }
        }
    }
    __syncthreads();                               // hb(h) ready

    // ---- stage C: gates = hb @ W2 * s1 (pad 640); u -> hb; g1 -> g1[][] ----
    {
        floatx4 acc[2][5] = {};
        gemm_stream<2,5,14>(W2F, &hb[0][0], 472, 0, lane, l15, quad, wn, acc);
        __syncthreads();                           // all hb(h) reads complete
        #pragma unroll
        for (int j = 0; j < 5; ++j) {
            const int colb = (wn + 8*j) * 16;      // wave-uniform, 0..624
            if (colb < 448) {                      // g0 -> u = sa * g0
                const int col = colb + l15;
                #pragma unroll
                for (int mt = 0; mt < 2; ++mt)
                    #pragma unroll
                    for (int r = 0; r < 4; ++r) {
                        const int row = mt*16 + quad*4 + r;
                        hb[row][col] = f2bf(bf2f(sa[row][col]) * (acc[mt][j][r] * s1));
                    }
            } else if (colb < 576) {               // g1o
                const int m = colb - 448 + l15;
                #pragma unroll
                for (int mt = 0; mt < 2; ++mt)
                    #pragma unroll
                    for (int r = 0; r < 4; ++r) {
                        const int row = mt*16 + quad*4 + r;
                        g1[row][m] = f2bf(acc[mt][j][r] * s1);
                    }
            }
        }
    }
    __syncthreads();                               // u/g1 ready; sa dead

    // ---- wmat build: wmat[(r*3+i)][m] = v[r][m][i] * g1[r][m] -> overlays sa ----
    {
        unsigned short* wmp = &sa[0][0];           // [96][136]
        #pragma unroll
        for (int e0 = 0; e0 < 3072; e0 += 512) {   // 32 rows * 96 float4
            int e4 = e0 + tid;
            int rl = e4 / 96;
            int c4 = (e4 - rl * 96) * 4;           // float index in v-row (0..383)
            float4 xv = *(const float4*)(x + (size_t)(n0 + rl) * 640 + 256 + c4);
            float vv[4] = {xv.x, xv.y, xv.z, xv.w};
            #pragma unroll
            for (int d = 0; d < 4; ++d) {
                int rem = c4 + d;
                int m = rem / 3;
                int i = rem - 3 * m;
                wmp[(rl * 3 + i) * 136 + m] = f2bf(vv[d] * bf2f(g1[rl][m]));
            }
        }
    }
    __syncthreads();                               // wmat ready

    // ---- stage D: o0 = u @ Wl0 * s1 -> LayerNorm -> out[:, :256] ----
    {
        floatx4 acc[2][2] = {};
        gemm_stream<2,2,14>(Wl0F, &hb[0][0], 472, 0, lane, l15, quad, wn, acc);
        #pragma unroll
        for (int mt = 0; mt < 2; ++mt)
            #pragma unroll
            for (int r = 0; r < 4; ++r) {
                float sv = 0.f, sq = 0.f;
                #pragma unroll
                for (int j = 0; j < 2; ++j) {
                    float v = acc[mt][j][r] * s1;
                    sv += v; sq += v * v;
                }
                #pragma unroll
                for (int off = 1; off <= 8; off <<= 1) {
                    sv += __shfl_xor(sv, off);
                    sq += __shfl_xor(sq, off);
                }
                if (l15 == 0) {
                    const int row = mt*16 + quad*4 + r;
                    red[row * 8 + wn]       = sv;
                    red[256 + row * 8 + wn] = sq;
                }
            }
        __syncthreads();                           // LN partials ready
        #pragma unroll
        for (int mt = 0; mt < 2; ++mt)
            #pragma unroll
            for (int r = 0; r < 4; ++r) {
                const int row = mt*16 + quad*4 + r;
                float ts = 0.f, tq = 0.f;
                #pragma unroll
                for (int w2 = 0; w2 < 8; ++w2) {
                    ts += red[row*8 + w2];
                    tq += red[256 + row*8 + w2];
                }
                float mu  = ts * (1.f/256.f);
                float var = tq * (1.f/256.f) - mu * mu;
                float rln = rsqrtf(var + 1e-6f);
                float* orow = out + (size_t)(n0 + row) * 640;
                #pragma unroll
                for (int j = 0; j < 2; ++j)
                    orow[(wn + 8*j)*16 + l15] = (acc[mt][j][r] * s1 - mu) * rln;
            }
    }
    __syncthreads();                               // stage-D red reads done before E writes red

    // ---- stage E: o1 = wmat @ Wl1 * s2 -> RMS over (3,128) -> out[:, 256:640] ----
    {
        floatx4 acc[6][1] = {};
        gemm_stream<6,1,4>(Wl1F, &sa[0][0] /*wmat*/, 136, 0, lane, l15, quad, wn, acc);
        #pragma unroll
        for (int mt = 0; mt < 6; ++mt)
            #pragma unroll
            for (int r = 0; r < 4; ++r) {
                float v = acc[mt][0][r] * s2;
                float q = v * v;
                #pragma unroll
                for (int off = 1; off <= 8; off <<= 1) q += __shfl_xor(q, off);
                if (l15 == 0) {
                    const int row = mt*16 + quad*4 + r;
                    red[row * 8 + wn] = q;
                }
            }
        __syncthreads();
        if (tid < 32) {                            // per-node rrms
            float s = 0.f;
            #pragma unroll
            for (int rr = 0; rr < 3; ++rr)
                #pragma unroll
                for (int w2 = 0; w2 < 8; ++w2)
                    s += red[(tid*3 + rr) * 8 + w2];
            red[768 + tid] = rsqrtf(s * (1.f/384.f) + 1e-6f);
        }
        __syncthreads();
        #pragma unroll
        for (int mt = 0; mt < 6; ++mt)
            #pragma unroll
            for (int r = 0; r < 4; ++r) {
                const int row = mt*16 + quad*4 + r;
                const int nl  = row / 3;
                const int i   = row - 3 * nl;
                const float rms = red[768 + nl];
                float* op = out + (size_t)(n0 + nl) * 640 + 256 + i;
                op[3 * (wn*16 + l15)] = acc[mt][0][r] * s2 * rms;
            }
    }
}

// ---------------------------------------------------------------- launch
extern "C" void kernel_launch(void* const* d_in, const int* in_sizes, int n_in,
                              void* d_out, int out_size, void* d_ws, size_t ws_size,
                              hipStream_t stream) {
    const float* x   = (const float*)d_in[0];
    const float* W1  = (const float*)d_in[1];
    const float* W2  = (const float*)d_in[2];
    const float* Wl0 = (const float*)d_in[3];
    const float* Wl1 = (const float*)d_in[4];
    float* out = (float*)d_out;
    char* ws = (char*)d_ws;

    unsigned short* W1F  = (unsigned short*)(ws + 0);         // 458,752 B (512x448)
    unsigned short* W2F  = (unsigned short*)(ws + 458752);    // 573,440 B (640x448)
    unsigned short* Wl0F = (unsigned short*)(ws + 1032192);   // 229,376 B (256x448)
    unsigned short* Wl1F = (unsigned short*)(ws + 1261568);   //  32,768 B (128x128)
    // peak ws: 1,294,336 bytes

    wcast_kernel<<<dim3(316), dim3(256), 0, stream>>>(W1, W2, Wl0, Wl1, W1F, W2F, Wl0F, Wl1F);
    fused_kernel<<<dim3(1024), dim3(512), 0, stream>>>(x, W1F, W2F, Wl0F, Wl1F, out);
}

// Round 8
// 231.107 us; speedup vs baseline: 1.0796x; 1.0206x over previous
//
#include <hip/hip_runtime.h>
#include <math.h>

// SegmentedTensorSquareSelfInteraction on MI355X (gfx950) — fused, streaming-B, pipelined.
// N=32768, MUL0=256, MUL1=128, G=64, INV_DIM=448, used gates=576, out=(N,640) fp32
//
// R8: R7's 2-deep ping-pong was defeated by the scheduler (VGPR stayed 64 -> loads sank
//     back to their consumers). Fix: sched_barrier(0) after every prefetch block pins
//     issue order -> both fragment sets stay live -> counted vmcnt waits (T4) emerge.
//     s_setprio(1) around MFMA clusters (T5): 2 blocks/CU at independent phases give
//     the CU scheduler role diversity to arbitrate.
//     Geometry unchanged: BM=32, 1x8 waves, MT=2, LDS 71,808 B, 2 blocks/CU.
//
// Two dispatches:
//  1. wcast : weights -> bf16 fragment order BF[tile][kc][lane][8], zero-padded tiles.
//  2. fused : per block of 32 nodes, whole chain, zero HBM intermediates:
//     A: s_all -> LDS sa[32][472]
//     B: h = silu(sa @ W1 * s1) -> LDS hb      (MT=2, NT=4, pad 512)
//     C: gates = hb @ W2 * s1 (MT=2, NT=5, pad 640); u = sa*g0 -> hb; g1 -> LDS
//        wmat[(r*3+i)][m] = v*g1 -> overlays sa ([96][136])
//     D: o0 = u @ Wl0 * s1 (MT=2, NT=2) -> LayerNorm -> out[:, :256]
//     E: o1 = wmat @ Wl1 * s2 (MT=6, NT=1) -> RMS over (3,128) -> out[:, 256:640]
// LDS: sa 30,208 + hb 30,208 + g1 8,192 + red 3,200 = 71,808 B -> 2 blocks/CU, 16 waves/CU.
// ws usage: 1,294,336 bytes (fragment-ordered bf16 weights only).

typedef float floatx4 __attribute__((ext_vector_type(4)));
typedef __bf16 bf16x8 __attribute__((ext_vector_type(8)));

__device__ __forceinline__ unsigned short f2bf(float f) {
    __bf16 h = (__bf16)f;                    // RNE; compiler can pair into v_cvt_pk_bf16_f32
    return __builtin_bit_cast(unsigned short, h);
}
__device__ __forceinline__ float bf2f(unsigned short u) {
    union { unsigned u; float f; } v; v.u = ((unsigned)u) << 16; return v.f;
}

// ---------------------------------------------------------------- weight cast
// Dst-indexed: thread owns one fragment octet (matrix, tile t, kc, lane) and writes
// one coalesced uint4.
__global__ __launch_bounds__(256) void wcast_kernel(
    const float* __restrict__ W1, const float* __restrict__ W2,
    const float* __restrict__ Wl0, const float* __restrict__ Wl1,
    unsigned short* __restrict__ W1F, unsigned short* __restrict__ W2F,
    unsigned short* __restrict__ Wl0F, unsigned short* __restrict__ Wl1F)
{
    int idx = blockIdx.x * 256 + threadIdx.x;   // one per 8 dst shorts
    const float* src; unsigned short* dst;
    int NKC, ld, colTrue, r;
    if (idx < 28672) {                        // W1F: 32 tiles x 14 kc x 64 lanes (512x448)
        r = idx; src = W1; dst = W1F; NKC = 14; ld = 448; colTrue = 448;
    } else if (idx < 64512) {                 // W2F: 40 tiles x 14 kc x 64 (640x448)
        r = idx - 28672; src = W2; dst = W2F; NKC = 14; ld = 832; colTrue = 576;
    } else if (idx < 78848) {                 // Wl0F: 16 tiles x 14 kc x 64 (256x448)
        r = idx - 64512; src = Wl0; dst = Wl0F; NKC = 14; ld = 256; colTrue = 256;
    } else if (idx < 80896) {                 // Wl1F: 8 tiles x 4 kc x 64 (128x128)
        r = idx - 78848; src = Wl1; dst = Wl1F; NKC = 4; ld = 128; colTrue = 128;
    } else return;
    int lane = r & 63, kc = (r >> 6) % NKC, t = (r >> 6) / NKC;
    int col = t * 16 + (lane & 15);
    int k0  = kc * 32 + (lane >> 4) * 8;
    unsigned short v[8];
    #pragma unroll
    for (int e = 0; e < 8; ++e)
        v[e] = (col < colTrue) ? f2bf(src[(size_t)(k0 + e) * ld + col]) : (unsigned short)0;
    *(uint4*)(dst + (size_t)r * 8) = *(const uint4*)v;
}

// ---------------------------------------------------------------- streaming GEMM core
// acc[MT][NT] += A_lds[rows] @ B (fragment-ordered global, L2-resident).
// 2-deep software pipeline with sched_barrier(0) fences: loads for the NEXT kc are
// issued and PINNED before the current kc's MFMA cluster (they cannot sink), so the
// waitcnt pass emits counted vmcnt waits and L2 latency hides under the MFMAs.
// s_setprio(1) biases the CU scheduler toward the MFMA-entering wave (T5).
template<int MT, int NT, int NKC>
__device__ __forceinline__ void gemm_stream(
    const unsigned short* __restrict__ BF,
    const unsigned short* __restrict__ Albs, const int ldsA, const int rowBase,
    const int lane, const int l15, const int quad, const int wn,
    floatx4 (&acc)[MT][NT])
{
    static_assert(NKC % 2 == 0, "pipeline assumes even NKC");
    const unsigned short* bp[NT];
    #pragma unroll
    for (int j = 0; j < NT; ++j)
        bp[j] = BF + ((size_t)(wn + 8 * j) * NKC * 64 + lane) * 8;
    const unsigned short* ap = Albs + (size_t)(rowBase + l15) * ldsA + quad * 8;

    bf16x8 a0[MT], b0[NT], a1[MT], b1[NT];
    #pragma unroll
    for (int mt = 0; mt < MT; ++mt) a0[mt] = *(const bf16x8*)(ap + mt * 16 * ldsA);
    #pragma unroll
    for (int j = 0; j < NT; ++j)    b0[j]  = *(const bf16x8*)(bp[j]);
    __builtin_amdgcn_sched_barrier(0);             // pin prologue loads

    #pragma unroll
    for (int kc2 = 0; kc2 < NKC / 2; ++kc2) {
        const int k1 = 2 * kc2 + 1, k2 = 2 * kc2 + 2;
        // prefetch kc=k1 into set1 — pinned above set0's MFMAs
        #pragma unroll
        for (int mt = 0; mt < MT; ++mt)
            a1[mt] = *(const bf16x8*)(ap + mt * 16 * ldsA + k1 * 32);
        #pragma unroll
        for (int j = 0; j < NT; ++j)
            b1[j] = *(const bf16x8*)(bp[j] + k1 * 512);
        __builtin_amdgcn_sched_barrier(0);
        // compute set0 (kc=2*kc2)
        __builtin_amdgcn_s_setprio(1);
        #pragma unroll
        for (int j = 0; j < NT; ++j)
            #pragma unroll
            for (int mt = 0; mt < MT; ++mt)
                acc[mt][j] = __builtin_amdgcn_mfma_f32_16x16x32_bf16(a0[mt], b0[j], acc[mt][j], 0, 0, 0);
        __builtin_amdgcn_s_setprio(0);
        // prefetch kc=k2 into set0 — pinned above set1's MFMAs
        if (k2 < NKC) {
            #pragma unroll
            for (int mt = 0; mt < MT; ++mt)
                a0[mt] = *(const bf16x8*)(ap + mt * 16 * ldsA + k2 * 32);
            #pragma unroll
            for (int j = 0; j < NT; ++j)
                b0[j] = *(const bf16x8*)(bp[j] + k2 * 512);
        }
        __builtin_amdgcn_sched_barrier(0);
        // compute set1 (kc=k1)
        __builtin_amdgcn_s_setprio(1);
        #pragma unroll
        for (int j = 0; j < NT; ++j)
            #pragma unroll
            for (int mt = 0; mt < MT; ++mt)
                acc[mt][j] = __builtin_amdgcn_mfma_f32_16x16x32_bf16(a1[mt], b1[j], acc[mt][j], 0, 0, 0);
        __builtin_amdgcn_s_setprio(0);
        __builtin_amdgcn_sched_barrier(0);
    }
}

// ---------------------------------------------------------------- fused megakernel
__global__ __launch_bounds__(512, 4) void fused_kernel(
    const float* __restrict__ x,
    const unsigned short* __restrict__ W1F,
    const unsigned short* __restrict__ W2F,
    const unsigned short* __restrict__ Wl0F,
    const unsigned short* __restrict__ Wl1F,
    float* __restrict__ out)
{
    __shared__ unsigned short sa[32][472];   // s_all; later wmat overlay [96][136]
    __shared__ unsigned short hb[32][472];   // h, then u
    __shared__ unsigned short g1[32][128];   // g1o gates
    __shared__ float red[800];               // LN sv[32][8] | sq @256 ; E q[96][8] ; rms @768

    const int tid  = threadIdx.x;
    const int lane = tid & 63;
    const int l15  = lane & 15;
    const int quad = lane >> 4;
    const int wn   = tid >> 6;      // 0..7 : N-tile = wn + 8*j (all waves own all rows)
    const int n0   = blockIdx.x * 32;

    const float s1 = 0.047245559f;  // 1/sqrt(448)
    const float s2 = 0.088388348f;  // 1/sqrt(128)

    // ---- stage A: s_all -> sa ----
    {
        const int r = tid >> 4, sub = tid & 15;    // 16 threads per row
        const float* xr = x + (size_t)(n0 + r) * 640;
        #pragma unroll
        for (int i = 0; i < 4; ++i) {              // s part: 64 float4 per row
            int c4 = i * 16 + sub;
            float4 f = *(const float4*)(xr + c4 * 4);
            uint2 p;
            p.x = (unsigned)f2bf(f.x) | ((unsigned)f2bf(f.y) << 16);
            p.y = (unsigned)f2bf(f.z) | ((unsigned)f2bf(f.w) << 16);
            *(uint2*)&sa[r][c4 * 4] = p;
        }
        const float* xv = xr + 256;
        #pragma unroll
        for (int i = 0; i < 4; ++i) {              // t0 part: 64 groups per row
            int g = i * 16 + sub;
            const float2* vg = (const float2*)(xv + 6 * g);
            float2 p0 = vg[0], p1 = vg[1], p2 = vg[2];
            float ax = p0.x, ay = p0.y, az = p1.x;
            float bx = p1.y, by = p2.x, bz = p2.y;
            float aa = ax*ax + ay*ay + az*az;
            float ab = ax*bx + ay*by + az*bz;
            float bb = bx*bx + by*by + bz*bz;
            const float ISQ3 = 0.57735026918962576f;
            const float SQ2  = 1.41421356237309505f;
            sa[r][256 + 3*g]     = f2bf(aa * ISQ3);
            sa[r][256 + 3*g + 1] = f2bf(SQ2 * ab * ISQ3);
            sa[r][256 + 3*g + 2] = f2bf(bb * ISQ3);
        }
    }
    __syncthreads();                               // sa ready

    // ---- stage B: h = silu(sa @ W1 * s1) -> hb  (pad 512, skip tiles >= 28) ----
    {
        floatx4 acc[2][4] = {};
        gemm_stream<2,4,14>(W1F, &sa[0][0], 472, 0, lane, l15, quad, wn, acc);
        #pragma unroll
        for (int j = 0; j < 4; ++j) {
            const int colb = (wn + 8*j) * 16;      // wave-uniform
            if (colb < 448) {
                const int col = colb + l15;
                #pragma unroll
                for (int mt = 0; mt < 2; ++mt)
                    #pragma unroll
                    for (int r = 0; r < 4; ++r) {
                        float v = acc[mt][j][r] * s1;
                        v = v / (1.f + __expf(-v));
                        hb[mt*16 + quad*4 + r][col] = f2bf(v);
                    }
            }
        }
    }
    __syncthreads();                               // hb(h) ready

    // ---- stage C: gates = hb @ W2 * s1 (pad 640); u -> hb; g1 -> g1[][] ----
    {
        floatx4 acc[2][5] = {};
        gemm_stream<2,5,14>(W2F, &hb[0][0], 472, 0, lane, l15, quad, wn, acc);
        __syncthreads();                           // all hb(h) reads complete
        #pragma unroll
        for (int j = 0; j < 5; ++j) {
            const int colb = (wn + 8*j) * 16;      // wave-uniform, 0..624
            if (colb < 448) {                      // g0 -> u = sa * g0
                const int col = colb + l15;
                #pragma unroll
                for (int mt = 0; mt < 2; ++mt)
                    #pragma unroll
                    for (int r = 0; r < 4; ++r) {
                        const int row = mt*16 + quad*4 + r;
                        hb[row][col] = f2bf(bf2f(sa[row][col]) * (acc[mt][j][r] * s1));
                    }
            } else if (colb < 576) {               // g1o
                const int m = colb - 448 + l15;
                #pragma unroll
                for (int mt = 0; mt < 2; ++mt)
                    #pragma unroll
                    for (int r = 0; r < 4; ++r) {
                        const int row = mt*16 + quad*4 + r;
                        g1[row][m] = f2bf(acc[mt][j][r] * s1);
                    }
            }
        }
    }
    __syncthreads();                               // u/g1 ready; sa dead

    // ---- wmat build: wmat[(r*3+i)][m] = v[r][m][i] * g1[r][m] -> overlays sa ----
    {
        unsigned short* wmp = &sa[0][0];           // [96][136]
        #pragma unroll
        for (int e0 = 0; e0 < 3072; e0 += 512) {   // 32 rows * 96 float4
            int e4 = e0 + tid;
            int rl = e4 / 96;
            int c4 = (e4 - rl * 96) * 4;           // float index in v-row (0..383)
            float4 xv = *(const float4*)(x + (size_t)(n0 + rl) * 640 + 256 + c4);
            float vv[4] = {xv.x, xv.y, xv.z, xv.w};
            #pragma unroll
            for (int d = 0; d < 4; ++d) {
                int rem = c4 + d;
                int m = rem / 3;
                int i = rem - 3 * m;
                wmp[(rl * 3 + i) * 136 + m] = f2bf(vv[d] * bf2f(g1[rl][m]));
            }
        }
    }
    __syncthreads();                               // wmat ready

    // ---- stage D: o0 = u @ Wl0 * s1 -> LayerNorm -> out[:, :256] ----
    {
        floatx4 acc[2][2] = {};
        gemm_stream<2,2,14>(Wl0F, &hb[0][0], 472, 0, lane, l15, quad, wn, acc);
        #pragma unroll
        for (int mt = 0; mt < 2; ++mt)
            #pragma unroll
            for (int r = 0; r < 4; ++r) {
                float sv = 0.f, sq = 0.f;
                #pragma unroll
                for (int j = 0; j < 2; ++j) {
                    float v = acc[mt][j][r] * s1;
                    sv += v; sq += v * v;
                }
                #pragma unroll
                for (int off = 1; off <= 8; off <<= 1) {
                    sv += __shfl_xor(sv, off);
                    sq += __shfl_xor(sq, off);
                }
                if (l15 == 0) {
                    const int row = mt*16 + quad*4 + r;
                    red[row * 8 + wn]       = sv;
                    red[256 + row * 8 + wn] = sq;
                }
            }
        __syncthreads();                           // LN partials ready
        #pragma unroll
        for (int mt = 0; mt < 2; ++mt)
            #pragma unroll
            for (int r = 0; r < 4; ++r) {
                const int row = mt*16 + quad*4 + r;
                float ts = 0.f, tq = 0.f;
                #pragma unroll
                for (int w2 = 0; w2 < 8; ++w2) {
                    ts += red[row*8 + w2];
                    tq += red[256 + row*8 + w2];
                }
                float mu  = ts * (1.f/256.f);
                float var = tq * (1.f/256.f) - mu * mu;
                float rln = rsqrtf(var + 1e-6f);
                float* orow = out + (size_t)(n0 + row) * 640;
                #pragma unroll
                for (int j = 0; j < 2; ++j)
                    orow[(wn + 8*j)*16 + l15] = (acc[mt][j][r] * s1 - mu) * rln;
            }
    }
    __syncthreads();                               // stage-D red reads done before E writes red

    // ---- stage E: o1 = wmat @ Wl1 * s2 -> RMS over (3,128) -> out[:, 256:640] ----
    {
        floatx4 acc[6][1] = {};
        gemm_stream<6,1,4>(Wl1F, &sa[0][0] /*wmat*/, 136, 0, lane, l15, quad, wn, acc);
        #pragma unroll
        for (int mt = 0; mt < 6; ++mt)
            #pragma unroll
            for (int r = 0; r < 4; ++r) {
                float v = acc[mt][0][r] * s2;
                float q = v * v;
                #pragma unroll
                for (int off = 1; off <= 8; off <<= 1) q += __shfl_xor(q, off);
                if (l15 == 0) {
                    const int row = mt*16 + quad*4 + r;
                    red[row * 8 + wn] = q;
                }
            }
        __syncthreads();
        if (tid < 32) {                            // per-node rrms
            float s = 0.f;
            #pragma unroll
            for (int rr = 0; rr < 3; ++rr)
                #pragma unroll
                for (int w2 = 0; w2 < 8; ++w2)
                    s += red[(tid*3 + rr) * 8 + w2];
            red[768 + tid] = rsqrtf(s * (1.f/384.f) + 1e-6f);
        }
        __syncthreads();
        #pragma unroll
        for (int mt = 0; mt < 6; ++mt)
            #pragma unroll
            for (int r = 0; r < 4; ++r) {
                const int row = mt*16 + quad*4 + r;
                const int nl  = row / 3;
                const int i   = row - 3 * nl;
                const float rms = red[768 + nl];
                float* op = out + (size_t)(n0 + nl) * 640 + 256 + i;
                op[3 * (wn*16 + l15)] = acc[mt][0][r] * s2 * rms;
            }
    }
}

// ---------------------------------------------------------------- launch
extern "C" void kernel_launch(void* const* d_in, const int* in_sizes, int n_in,
                              void* d_out, int out_size, void* d_ws, size_t ws_size,
                              hipStream_t stream) {
    const float* x   = (const float*)d_in[0];
    const float* W1  = (const float*)d_in[1];
    const float* W2  = (const float*)d_in[2];
    const float* Wl0 = (const float*)d_in[3];
    const float* Wl1 = (const float*)d_in[4];
    float* out = (float*)d_out;
    char* ws = (char*)d_ws;

    unsigned short* W1F  = (unsigned short*)(ws + 0);         // 458,752 B (512x448)
    unsigned short* W2F  = (unsigned short*)(ws + 458752);    // 573,440 B (640x448)
    unsigned short* Wl0F = (unsigned short*)(ws + 1032192);   // 229,376 B (256x448)
    unsigned short* Wl1F = (unsigned short*)(ws + 1261568);   //  32,768 B (128x128)
    // peak ws: 1,294,336 bytes

    wcast_kernel<<<dim3(316), dim3(256), 0, stream>>>(W1, W2, Wl0, Wl1, W1F, W2F, Wl0F, Wl1F);
    fused_kernel<<<dim3(1024), dim3(512), 0, stream>>>(x, W1F, W2F, Wl0F, Wl1F, out);
}